// Round 15
// baseline (586.775 us; speedup 1.0000x reference)
//
#include <hip/hip_runtime.h>

#define BB 32
#define CC 129
#define TT 1000
#define DD 256
#define NN 64
#define NLY 4

// ---------------- workspace layout (floats) ----------------
// h occupies [0, 8192000). P/Q/L/R live OUT of h so the powers chain can run
// CONCURRENTLY with embed (which writes all of h).
#define OFF_H    0
#define OFF_K    8192000
#define OFF_INV  9232384
#define OFF_MHA  9264384
#define OFF_P    10000000
#define OFF_Q    10140000
#define OFF_L    10280000
#define OFF_R    12380000

typedef __attribute__((ext_vector_type(8))) short bf16x8;
typedef __attribute__((ext_vector_type(8))) _Float16 f16x8;
typedef __attribute__((ext_vector_type(4))) float f32x4;
typedef __attribute__((ext_vector_type(16))) float f32x16;

__device__ __forceinline__ unsigned short f2bf(float x) {
    unsigned int u = __float_as_uint(x);
    unsigned int r = (u + 0x7FFF + ((u >> 16) & 1)) >> 16;
    return (unsigned short)r;
}
__device__ __forceinline__ float bf2f(unsigned short b) {
    return __uint_as_float(((unsigned int)b) << 16);
}
__device__ __forceinline__ unsigned short f2h(float x) {
    _Float16 v = (_Float16)x;
    return *(unsigned short*)&v;
}
__device__ __forceinline__ float h2f(unsigned short b) {
    _Float16 v = *(_Float16*)&b;
    return (float)v;
}

// ============ Ad build (block 0) + w_in prep (1..256) + MHA qprep (257) ============
// Sherman-Morrison + Newton polish (HW-verified R4/R7/R8/R10-R14). qprep as block 257.
#define BST 68
__global__ __launch_bounds__(256, 1) void k_build_ad(const float* __restrict__ logdt,
                                                     float* __restrict__ P,
                                                     const float* __restrict__ w_in,
                                                     unsigned short* __restrict__ whi,
                                                     unsigned short* __restrict__ wlo,
                                                     const float* __restrict__ cls,
                                                     const float* __restrict__ inw,
                                                     const float* __restrict__ inb,
                                                     float* __restrict__ qk,
                                                     float* __restrict__ qb) {
    int tid = threadIdx.x;
    if (blockIdx.x == 257) {           // ---- qprep path ----
        __shared__ float Qv[256];
        int j = tid;
        float a = inb[j];
        for (int i = 0; i < 256; ++i) a = fmaf(inw[j * DD + i], cls[i], a);
        Qv[j] = a;
        __syncthreads();
        const float scale = 0.17677669529663687f; // 1/sqrt(32)
        for (int idx = tid; idx < 8 * 256; idx += 256) {
            int hh = idx >> 8, i = idx & 255;
            float s = 0.f;
            for (int jj = 0; jj < 32; ++jj)
                s = fmaf(Qv[hh * 32 + jj], inw[(DD + hh * 32 + jj) * DD + i], s);
            qk[idx] = s * scale;
        }
        if (tid < 8) {
            int hh = tid;
            float s = 0.f;
            for (int jj = 0; jj < 32; ++jj)
                s = fmaf(Qv[hh * 32 + jj], inb[DD + hh * 32 + jj], s);
            qb[hh] = s * scale;
        }
        return;
    }
    if (blockIdx.x != 0) {             // ---- w_in split-bf16 prep ----
        int d = blockIdx.x - 1;      // 0..255
        int c = tid;
        if (c < 136) {
            float v = (c < CC) ? w_in[d * CC + c] : 0.f;
            unsigned short h = f2bf(v);
            whi[d * 136 + c] = h;
            wlo[d * 136 + c] = f2bf(v - bf2f(h));
        }
        return;
    }
    __shared__ __align__(16) float Ms[64 * BST];
    __shared__ __align__(16) float Vs[64 * BST];
    __shared__ __align__(16) float Ws[64 * BST];
    float dt = expf(logdt[0]);
    dt = fminf(fmaxf(dt, 1e-4f), 0.1f);
    float hh = dt * 0.5f;
    int w = tid >> 6, r = tid & 63;
    {
        float Pr = sqrtf(1.f + 2.f * (float)r);
#pragma unroll
        for (int jj = 0; jj < 16; ++jj) {
            int j = w * 16 + jj;
            float av;
            if (r == j) av = -((float)r + 0.5f);
            else { float m = Pr * sqrtf(1.f + 2.f * (float)j); av = (r > j) ? -m : m; }
            Ms[r * BST + j] = ((r == j) ? 1.f : 0.f) - hh * av;
        }
    }
    if (tid < 64) {
        int lane = tid;
        float x[64], u[64];
        float s = 0.f, su = 0.f;
#pragma unroll
        for (int i = 0; i < 64; ++i) {
            const float Pi = sqrtf(2.f * (float)i + 1.f);
            float Lii = fmaf(3.f * ((float)i + 0.5f), hh, 1.f);
            float rinv = 1.f / Lii;
            float c = 2.f * hh * Pi;
            float del = (lane == i) ? 1.f : 0.f;
            x[i] = (del - c * s) * rinv;
            s = fmaf(Pi, x[i], s);
            u[i] = (Pi - c * su) * rinv;
            su = fmaf(Pi, u[i], su);
        }
        float beta = hh / (1.f - hh * su);
        float bv = beta * s;
#pragma unroll
        for (int i = 0; i < 64; ++i)
            Vs[i * BST + lane] = fmaf(bv, u[i], x[i]);
    }
    __syncthreads();
    // ---- Newton refine, step A: W = 2I - M*V ----
    {
        int tr = (tid >> 4) << 2, tc = (tid & 15) << 2;
        float acc[4][4];
#pragma unroll
        for (int u = 0; u < 4; ++u)
#pragma unroll
            for (int v = 0; v < 4; ++v) acc[u][v] = 0.f;
        for (int k0 = 0; k0 < 64; k0 += 4) {
            f32x4 av[4], bv[4];
#pragma unroll
            for (int u = 0; u < 4; ++u) av[u] = *(const f32x4*)&Ms[(tr + u) * BST + k0];
#pragma unroll
            for (int kk = 0; kk < 4; ++kk) bv[kk] = *(const f32x4*)&Vs[(k0 + kk) * BST + tc];
#pragma unroll
            for (int u = 0; u < 4; ++u)
#pragma unroll
                for (int kk = 0; kk < 4; ++kk)
#pragma unroll
                    for (int v = 0; v < 4; ++v)
                        acc[u][v] = fmaf(av[u][kk], bv[kk][v], acc[u][v]);
        }
        __syncthreads();
#pragma unroll
        for (int u = 0; u < 4; ++u)
#pragma unroll
            for (int v = 0; v < 4; ++v)
                Ws[(tr + u) * BST + tc + v] =
                    (((tr + u) == (tc + v)) ? 2.f : 0.f) - acc[u][v];
    }
    __syncthreads();
    // ---- Newton refine, step B: Ad = 2*(V*W) - I ; also P[0] = I ----
    {
        int tr = (tid >> 4) << 2, tc = (tid & 15) << 2;
        float acc[4][4];
#pragma unroll
        for (int u = 0; u < 4; ++u)
#pragma unroll
            for (int v = 0; v < 4; ++v) acc[u][v] = 0.f;
        for (int k0 = 0; k0 < 64; k0 += 4) {
            f32x4 av[4], bv[4];
#pragma unroll
            for (int u = 0; u < 4; ++u) av[u] = *(const f32x4*)&Vs[(tr + u) * BST + k0];
#pragma unroll
            for (int kk = 0; kk < 4; ++kk) bv[kk] = *(const f32x4*)&Ws[(k0 + kk) * BST + tc];
#pragma unroll
            for (int u = 0; u < 4; ++u)
#pragma unroll
                for (int kk = 0; kk < 4; ++kk)
#pragma unroll
                    for (int v = 0; v < 4; ++v)
                        acc[u][v] = fmaf(av[u][kk], bv[kk][v], acc[u][v]);
        }
#pragma unroll
        for (int u = 0; u < 4; ++u)
#pragma unroll
            for (int v = 0; v < 4; ++v) {
                int rr = tr + u, cc = tc + v;
                float eye = (rr == cc) ? 1.f : 0.f;
                P[rr * 64 + cc] = eye;
                P[4096 + rr * 64 + cc] = 2.f * acc[u][v] - eye;
            }
    }
}

// ============ mm64x / powm (512-thread, HW-verified R10-R14) ============
#define PLDA 68
__device__ __forceinline__ void mm64x(float* D, const float* A, const float* B) {
    int tr = (threadIdx.x >> 4) << 1, tc = (threadIdx.x & 15) << 2;
    float acc[2][4];
#pragma unroll
    for (int u = 0; u < 2; ++u)
#pragma unroll
        for (int v = 0; v < 4; ++v) acc[u][v] = 0.f;
#pragma unroll 2
    for (int k0 = 0; k0 < 64; k0 += 4) {
        f32x4 av[2], bv[4];
#pragma unroll
        for (int u = 0; u < 2; ++u) av[u] = *(const f32x4*)&A[(tr + u) * PLDA + k0];
#pragma unroll
        for (int kk = 0; kk < 4; ++kk) bv[kk] = *(const f32x4*)&B[(k0 + kk) * PLDA + tc];
#pragma unroll
        for (int u = 0; u < 2; ++u)
#pragma unroll
            for (int kk = 0; kk < 4; ++kk)
#pragma unroll
                for (int v = 0; v < 4; ++v)
                    acc[u][v] = fmaf(av[u][kk], bv[kk][v], acc[u][v]);
    }
    __syncthreads();
#pragma unroll
    for (int u = 0; u < 2; ++u)
#pragma unroll
        for (int v = 0; v < 4; ++v) D[(tr + u) * PLDA + tc + v] = acc[u][v];
    __syncthreads();
}

__device__ float* powm(float* U, float* V, const float* base, int e) {
    for (int i = threadIdx.x; i < 4096; i += 512)
        U[(i >> 6) * PLDA + (i & 63)] = base[(i >> 6) * PLDA + (i & 63)];
    __syncthreads();
    float* X = U; float* Y = V;
    for (int bit = 30 - __builtin_clz(e); bit >= 0; --bit) {
        mm64x(Y, X, X); { float* t = X; X = Y; Y = t; }
        if ((e >> bit) & 1) { mm64x(Y, X, base); float* t = X; X = Y; Y = t; }
    }
    return X;
}

// ============ MERGED powers (blocks 0-61) + embed (blocks 62-573) ============
// LDS 52224 B (AdS-reuse eliminates BaseS; bitwise-identical P/Q). Duration is
// bounded by the powers serial chain (occupancy-invariant per R13/R14 A/B) — left as-is.
__global__ __launch_bounds__(512, 4) void k_pe(float* __restrict__ P, float* __restrict__ Q,
                                               const float* __restrict__ x,
                                               const unsigned short* __restrict__ whi,
                                               const unsigned short* __restrict__ wlo,
                                               const float* __restrict__ w_in,
                                               const float* __restrict__ b_in,
                                               const float* __restrict__ lng,
                                               const float* __restrict__ lnb,
                                               float* __restrict__ h,
                                               float* __restrict__ invn) {
    __shared__ __align__(16) char smem[52224];
    int tid = threadIdx.x;
    if (blockIdx.x < 62) {
        // ---- powers path (3 LDS buffers: AdS, Ub, Vb) ----
        float* AdS = (float*)smem;
        float* Ub  = AdS + 64 * PLDA;
        float* Vb  = Ub + 64 * PLDA;
        int bid = blockIdx.x;
        if (bid == 61) {   // Q[0] = I
            for (int i = tid; i < 4096; i += 512) Q[i] = ((i >> 6) == (i & 63)) ? 1.f : 0.f;
            return;
        }
        const float* Ad = P + 4096;
        for (int i = tid; i < 4096; i += 512) AdS[(i >> 6) * PLDA + (i & 63)] = Ad[i];
        __syncthreads();
        float* res;
        float* out;
        if (bid < 30) {                    // P[2+bid] = Ad^(2+bid)
            res = powm(Ub, Vb, AdS, bid + 2);
            out = P + (size_t)(bid + 2) * 4096;
        } else {                           // Q[i] = (Ad^32)^i, i = bid-29 in 1..31
            int iq = bid - 29;
            float* b32 = powm(Ub, Vb, AdS, 32);
            // AdS (the Ad copy) is dead now; reuse it as the base-32 buffer.
            for (int i = tid; i < 4096; i += 512)
                AdS[(i >> 6) * PLDA + (i & 63)] = b32[(i >> 6) * PLDA + (i & 63)];
            __syncthreads();
            res = powm(Ub, Vb, AdS, iq);
            out = Q + (size_t)iq * 4096;
        }
        for (int i = tid; i < 4096; i += 512) out[i] = res[(i >> 6) * PLDA + (i & 63)];
        return;
    }
    // ---- embed path (verbatim R10-R14 body; LDS via smem overlay, 42240 B) ----
    unsigned short* xs_h = (unsigned short*)smem;
    unsigned short* xs_l = (unsigned short*)(smem + 16640);
    float* xlasts = (float*)(smem + 33280);
    float* w128s  = (float*)(smem + 33536);
    float* biass  = (float*)(smem + 34560);
    float* gs     = (float*)(smem + 35584);
    float* bs     = (float*)(smem + 36608);
    float (*ps)[8]  = (float(*)[8])(smem + 37632);
    float (*ps2)[8] = (float(*)[8])(smem + 39680);
    float* mstat  = (float*)(smem + 41728);
    float* rstat  = (float*)(smem + 41984);
    int e = blockIdx.x - 62;
    int b = e >> 4, t0 = (e & 15) * 64;
    for (int i = tid; i < CC * 64; i += 512) {
        int c = i >> 6, tl = i & 63;
        int t = t0 + tl;
        float v = (t < TT) ? x[(size_t)(b * CC + c) * TT + t] : 0.f;
        if (c == 128) {
            xlasts[tl] = v;
        } else {
            unsigned short hh = f2bf(v);
            xs_h[tl * 130 + c] = hh;
            xs_l[tl * 130 + c] = f2bf(v - bf2f(hh));
        }
    }
    if (tid < 256) {
        w128s[tid] = w_in[tid * CC + 128];
        biass[tid] = b_in[tid];
        gs[tid] = lng[tid];
        bs[tid] = lnb[tid];
    }
    __syncthreads();
    int wave = tid >> 6, lane = tid & 63;
    int tn = lane & 15, q = lane >> 4;
    int d0w = wave * 32;
    f32x4 acc[4][2];
#pragma unroll
    for (int nt = 0; nt < 4; ++nt)
#pragma unroll
        for (int mt = 0; mt < 2; ++mt) acc[nt][mt] = (f32x4){0.f, 0.f, 0.f, 0.f};
#pragma unroll
    for (int kc = 0; kc < 4; ++kc) {
        int c0 = kc * 32;
        bf16x8 Ah[2], Al[2];
#pragma unroll
        for (int mt = 0; mt < 2; ++mt) {
            int base = (d0w + mt * 16 + tn) * 136 + c0 + 8 * q;
            Ah[mt] = *(const bf16x8*)&whi[base];
            Al[mt] = *(const bf16x8*)&wlo[base];
        }
#pragma unroll
        for (int nt = 0; nt < 4; ++nt) {
            const unsigned int* ph = (const unsigned int*)&xs_h[(nt * 16 + tn) * 130 + c0 + 8 * q];
            const unsigned int* pl = (const unsigned int*)&xs_l[(nt * 16 + tn) * 130 + c0 + 8 * q];
            union { bf16x8 v; unsigned int u[4]; } Bh, Bl;
            Bh.u[0] = ph[0]; Bh.u[1] = ph[1]; Bh.u[2] = ph[2]; Bh.u[3] = ph[3];
            Bl.u[0] = pl[0]; Bl.u[1] = pl[1]; Bl.u[2] = pl[2]; Bl.u[3] = pl[3];
#pragma unroll
            for (int mt = 0; mt < 2; ++mt) {
                acc[nt][mt] = __builtin_amdgcn_mfma_f32_16x16x32_bf16(Al[mt], Bh.v, acc[nt][mt], 0, 0, 0);
                acc[nt][mt] = __builtin_amdgcn_mfma_f32_16x16x32_bf16(Ah[mt], Bl.v, acc[nt][mt], 0, 0, 0);
                acc[nt][mt] = __builtin_amdgcn_mfma_f32_16x16x32_bf16(Ah[mt], Bh.v, acc[nt][mt], 0, 0, 0);
            }
        }
    }
#pragma unroll
    for (int nt = 0; nt < 4; ++nt) {
        float xl = xlasts[nt * 16 + tn];
        float s = 0.f, s2 = 0.f;
#pragma unroll
        for (int mt = 0; mt < 2; ++mt) {
#pragma unroll
            for (int r = 0; r < 4; ++r) {
                int d = d0w + mt * 16 + 4 * q + r;
                float v = acc[nt][mt][r] + biass[d] + w128s[d] * xl;
                acc[nt][mt][r] = v;
                s += v; s2 = fmaf(v, v, s2);
            }
        }
        s += __shfl_xor(s, 16); s += __shfl_xor(s, 32);
        s2 += __shfl_xor(s2, 16); s2 += __shfl_xor(s2, 32);
        if (q == 0) { ps[nt * 16 + tn][wave] = s; ps2[nt * 16 + tn][wave] = s2; }
    }
    __syncthreads();
    if (tid < 64) {
        float s = 0.f, s2 = 0.f;
#pragma unroll
        for (int k = 0; k < 8; ++k) { s += ps[tid][k]; s2 += ps2[tid][k]; }
        float mean = s * (1.f / 256.f);
        float ex2 = s2 * (1.f / 256.f);
        mstat[tid] = mean;
        rstat[tid] = 1.f / sqrtf(ex2 - mean * mean + 1e-5f);
    }
    __syncthreads();
    float sq[4] = {0.f, 0.f, 0.f, 0.f};
#pragma unroll
    for (int mt = 0; mt < 2; ++mt) {
#pragma unroll
        for (int r = 0; r < 4; ++r) {
            int d = d0w + mt * 16 + 4 * q + r;
            float gd = gs[d], bd = bs[d];
            float freq = expf((float)(d & ~1) * (-9.210340371976184f / 256.f));
            int odd = d & 1;
#pragma unroll
            for (int nt = 0; nt < 4; ++nt) {
                int tl = nt * 16 + tn;
                int t = t0 + tl;
                float o = (acc[nt][mt][r] - mstat[tl]) * rstat[tl] * gd + bd;
                float ang = (float)t * freq;
                o += odd ? cosf(ang) : sinf(ang);
                if (t < TT) h[((size_t)(b * DD + d)) * TT + t] = o;
                sq[nt] = fmaf(o, o, sq[nt]);
            }
        }
    }
#pragma unroll
    for (int nt = 0; nt < 4; ++nt) {
        float s = sq[nt];
        s += __shfl_xor(s, 16); s += __shfl_xor(s, 32);
        if (q == 0) ps[nt * 16 + tn][wave] = s;
    }
    __syncthreads();
    if (tid < 64) {
        int t = t0 + tid;
        if (t < TT) {
            float s = 0.f;
#pragma unroll
            for (int k = 0; k < 8; ++k) s += ps[tid][k];
            invn[b * TT + t] = 1.f / (sqrtf(s) + 1e-8f);
        }
    }
}

// ============ L / R ============
__global__ __launch_bounds__(256) void k_lr(const float* __restrict__ P, const float* __restrict__ Q,
                                            const float* __restrict__ s4B, const float* __restrict__ s4C,
                                            float* __restrict__ L, float* __restrict__ R) {
    __shared__ float Ms[4096];
    int l = blockIdx.x >> 6, rem = blockIdx.x & 63, which = rem >> 5, idx = rem & 31;
    const float* M = which ? (P + (size_t)idx * 4096)
                           : (Q + (size_t)idx * 4096);
    for (int i = threadIdx.x; i < 4096; i += 256) Ms[i] = M[i];
    __syncthreads();
    int d = threadIdx.x;
    if (which == 0) {
        float* dst = L + (((size_t)(l * DD + d) * 32 + idx) * 64);
        for (int jc = 0; jc < 8; ++jc) {
            float acc[8];
#pragma unroll
            for (int u = 0; u < 8; ++u) acc[u] = 0.f;
            for (int i = 0; i < 64; ++i) {
                float bv = s4B[(l * NN + i) * DD + d];
#pragma unroll
                for (int u = 0; u < 8; ++u)
                    acc[u] = fmaf(bv, Ms[i * 64 + jc * 8 + u], acc[u]);
            }
#pragma unroll
            for (int u = 0; u < 8; ++u) dst[jc * 8 + u] = acc[u];
        }
    } else {
        float* dst = R + (((size_t)(l * DD + d) * 32 + idx) * 64);
        const float* Cp = s4C + (size_t)(l * DD + d) * NN;
        for (int ic = 0; ic < 8; ++ic) {
            float acc[8];
#pragma unroll
            for (int u = 0; u < 8; ++u) acc[u] = 0.f;
            for (int j = 0; j < 64; ++j) {
                float cv = Cp[j];
#pragma unroll
                for (int u = 0; u < 8; ++u)
                    acc[u] = fmaf(Ms[(ic * 8 + u) * 64 + j], cv, acc[u]);
            }
#pragma unroll
            for (int u = 0; u < 8; ++u) dst[ic * 8 + u] = acc[u];
        }
    }
}

// ============ kernel assembly ============
__global__ __launch_bounds__(256) void k_kker(const float* __restrict__ L, const float* __restrict__ R,
                                              float* __restrict__ kk) {
    __shared__ float Ls[32 * 65], Rs[32 * 65];
    int l = blockIdx.x >> 8, d = blockIdx.x & 255;
    const float* Lp = L + ((size_t)(l * DD + d) * 32) * 64;
    const float* Rp = R + ((size_t)(l * DD + d) * 32) * 64;
    for (int i = threadIdx.x; i < 2048; i += 256) {
        int row = i >> 6, col = i & 63;
        Ls[row * 65 + col] = Lp[i];
        Rs[row * 65 + col] = Rp[i];
    }
    __syncthreads();
    for (int t = threadIdx.x; t < TT; t += 256) {
        int kq = t >> 5, r = t & 31;
        const float* lr = &Ls[kq * 65];
        const float* rr = &Rs[r * 65];
        float a = 0.f;
#pragma unroll 8
        for (int m = 0; m < 64; ++m) a = fmaf(lr[m], rr[m], a);
        kk[(size_t)(l * DD + d) * TT + t] = a * expf(-0.01f * (float)t);
    }
}

// ============ LayerNorm (in-place), single-pass ============
__global__ __launch_bounds__(256) void k_ln(const float* __restrict__ in, const float* __restrict__ g,
                                            const float* __restrict__ bia, float* __restrict__ out,
                                            float* __restrict__ invn) {
    int b = blockIdx.y, t0 = blockIdx.x * 64;
    int w = threadIdx.x >> 6, lane = threadIdx.x & 63;
    int t = t0 + lane;
    __shared__ float ps[4][64], ps2[4][64];
    float v[64];
    float s = 0.f, s2 = 0.f;
    bool ok = t < TT;
#pragma unroll
    for (int k = 0; k < 64; ++k) {
        float x = ok ? in[(size_t)(b * DD + (w + 4 * k)) * TT + t] : 0.f;
        v[k] = x;
        s += x; s2 = fmaf(x, x, s2);
    }
    ps[w][lane] = s; ps2[w][lane] = s2;
    __syncthreads();
    float mean = (ps[0][lane] + ps[1][lane] + ps[2][lane] + ps[3][lane]) * (1.f / 256.f);
    float ex2  = (ps2[0][lane] + ps2[1][lane] + ps2[2][lane] + ps2[3][lane]) * (1.f / 256.f);
    float rstd = 1.f / sqrtf(ex2 - mean * mean + 1e-5f);
    float sq = 0.f;
    if (ok) {
#pragma unroll
        for (int k = 0; k < 64; ++k) {
            int d = w + 4 * k;
            float o = (v[k] - mean) * rstd * g[d] + bia[d];
            out[(size_t)(b * DD + d) * TT + t] = o;
            sq = fmaf(o, o, sq);
        }
    }
    __syncthreads();
    ps[w][lane] = sq;
    __syncthreads();
    if (w == 0 && ok) {
        float tot = ps[0][lane] + ps[1][lane] + ps[2][lane] + ps[3][lane];
        invn[b * TT + t] = 1.f / (sqrtf(tot) + 1e-8f);
    }
}

__device__ __forceinline__ float gelu_exact(float y) {
    return 0.5f * y * (1.f + erff(y * 0.7071067811865476f));
}

// ============ MFMA conv v4: 8-batch blocks, grid (DD, 4) ============
// v3 (16-batch) was 2 blocks/CU = 16 waves/CU, ~3x its HBM floor. v4 keeps the
// SAME verified structure (wave-uniform u0>=0 guard, no divergent zeroing) and
// narrows batches 16->8: bp = nn&7 (always in-bounds), epilogue writes brow<8
// only (rows 8-31 are discarded duplicates; written accumulations bitwise-
// identical to v1/v3). LDS ~20.7KB -> 4 blocks/CU, 32 waves/CU. Grid-wide MFMA
// waste ~0.5us (MfmaUtil ~5%) — negligible.
#define XS2 1032
__global__ __launch_bounds__(512) void k_conv32(float* __restrict__ h, const float* __restrict__ kk,
                                                const float* __restrict__ invn,
                                                const float* __restrict__ s4D, int layer) {
    __shared__ unsigned short Xs[8 * XS2];
    __shared__ unsigned int pks[1056];
    int d = blockIdx.x;
    int bbase = blockIdx.y * 8;
    int tid = threadIdx.x;
    const float* krow = kk + (size_t)(layer * DD + d) * TT;
    for (int mm = tid; mm < 1056; mm += 512) {
        int m = mm - 32;
        float klo = (m >= 0 && m < TT) ? krow[m] : 0.f;
        float kpr = (m >= 1 && m <= TT) ? krow[m - 1] : 0.f;
        pks[mm] = (unsigned int)f2h(klo) | ((unsigned int)f2h(kpr) << 16);
    }
    for (int ii = tid; ii < 8 * 512; ii += 512) {
        int bb = ii >> 9;                       // 0..7 local batch
        int tp = (ii & 511) * 2;
        const float* hrow = h + ((size_t)(bbase + bb) * DD + d) * TT;
        const float* ivr = invn + (size_t)(bbase + bb) * TT;
        float v0 = (tp < TT) ? hrow[tp] * ivr[tp] : 0.f;
        float v1 = (tp + 1 < TT) ? hrow[tp + 1] * ivr[tp + 1] : 0.f;
        ((unsigned int*)Xs)[(bb * XS2 + tp) >> 1] = (unsigned int)f2h(v0) | ((unsigned int)f2h(v1) << 16);
    }
    __syncthreads();
    float gate = 1.f / (1.f + expf(-s4D[layer * DD + d]));
    int wave = tid >> 6, lane = tid & 63;
    int nn = lane & 31, kq8 = (lane >> 5) << 3;
    int bp = nn & 7;                            // A-row batch (rows 8-31 duplicate 0-7)
    for (int pass = 0; pass < 2; ++pass) {
        int G = pass ? (15 - wave) : wave;
        int jlo = 2 * G;
        f32x16 acc[2];
#pragma unroll
        for (int m = 0; m < 2; ++m)
#pragma unroll
            for (int r = 0; r < 16; ++r) acc[m][r] = 0.f;
        for (int D = 32 * jlo + 32; D >= -16; D -= 16) {
            int S32 = D + nn - kq8 + 32;
            union { f16x8 v; unsigned int u[4]; } bh;
            bh.u[0] = pks[S32];
            bh.u[1] = pks[S32 - 2];
            bh.u[2] = pks[S32 - 4];
            bh.u[3] = pks[S32 - 6];
#pragma unroll
            for (int m = 0; m < 2; ++m) {
                int u0 = (jlo + m) * 32 - D;
                if (u0 >= 0) {
                    const f16x8 ah = *(const f16x8*)&Xs[bp * XS2 + u0 + kq8];
                    acc[m] = __builtin_amdgcn_mfma_f32_32x32x16_f16(ah, bh.v, acc[m], 0, 0, 0);
                }
            }
        }
#pragma unroll
        for (int m = 0; m < 2; ++m) {
            int t = (jlo + m) * 32 + nn;
            if (t < TT) {
#pragma unroll
                for (int r = 0; r < 16; ++r) {
                    int brow = (r & 3) + 8 * (r >> 2) + 4 * (lane >> 5);
                    if (brow < 8) {             // rows 8-31 are discarded duplicates
                        size_t ix = ((size_t)(bbase + brow) * DD + d) * TT + t;
                        float y = acc[m][r];
                        float xn = h2f(Xs[brow * XS2 + t]);
                        float ho = h[ix];       // L2-hot re-read (exact residual)
                        h[ix] = gelu_exact(y + xn * gate) + 1.1f * ho;
                    }
                }
            }
        }
    }
}

// ============ MHA scores ============
__global__ __launch_bounds__(128) void k_scores(const float* __restrict__ h, const float* __restrict__ cls,
                                                const float* __restrict__ qkw, const float* __restrict__ qbw,
                                                float* __restrict__ sc) {
    __shared__ float qks[8 * 256];
    int b = blockIdx.y;
    int s = blockIdx.x * 128 + threadIdx.x;
    for (int i = threadIdx.x; i < 2048; i += 128) qks[i] = qkw[i];
    __syncthreads();
    if (s >= TT + 1) return;
    float acc[8];
#pragma unroll
    for (int hh = 0; hh < 8; ++hh) acc[hh] = qbw[hh];
    if (s == 0) {
        for (int i = 0; i < 256; ++i) {
            float v = cls[i];
#pragma unroll
            for (int hh = 0; hh < 8; ++hh) acc[hh] = fmaf(qks[hh * 256 + i], v, acc[hh]);
        }
    } else {
        const float* hb = h + (size_t)b * DD * TT + (s - 1);
        for (int i = 0; i < 256; ++i) {
            float v = hb[(size_t)i * TT];
#pragma unroll
            for (int hh = 0; hh < 8; ++hh) acc[hh] = fmaf(qks[hh * 256 + i], v, acc[hh]);
        }
    }
#pragma unroll
    for (int hh = 0; hh < 8; ++hh) sc[(size_t)(b * 8 + hh) * 1024 + s] = acc[hh];
}

// ============ ctx stage 1 with FUSED softmax, shuffle-free (HW-verified R12-R14) ============
__global__ __launch_bounds__(256) void k_ctx1(const float* __restrict__ h,
                                              const float* __restrict__ sc,
                                              float* __restrict__ ctx1,
                                              float* __restrict__ att0) {
    __shared__ float as[8][256];
    __shared__ float hs[32][251];
    __shared__ float mrow[8], invrow[8];
    int i0 = blockIdx.x * 32, tc = blockIdx.y, b = blockIdx.z;
    int tid = threadIdx.x;
    {
        int hh = tid >> 5, l32 = tid & 31;
        const float* p = sc + (size_t)(b * 8 + hh) * 1024;
        float m = -3.4e38f;
        for (int s = l32; s < TT + 1; s += 32) m = fmaxf(m, p[s]);
#pragma unroll
        for (int off = 16; off; off >>= 1) m = fmaxf(m, __shfl_xor(m, off, 32));
        float sum = 0.f;
        for (int s = l32; s < TT + 1; s += 32) sum += expf(p[s] - m);
#pragma unroll
        for (int off = 16; off; off >>= 1) sum += __shfl_xor(sum, off, 32);
        if (l32 == 0) { mrow[hh] = m; invrow[hh] = 1.f / sum; }
    }
    __syncthreads();
    int sbase = tc * 250 + 1;
    for (int idx = tid; idx < 2048; idx += 256) {
        int hh = idx >> 8, u = idx & 255;
        as[hh][u] = (u < 250)
            ? expf(sc[(size_t)(b * 8 + hh) * 1024 + sbase + u] - mrow[hh]) * invrow[hh]
            : 0.f;
    }
    // stage h tile [32 i][250 t], coalesced one row per iteration
    for (int row = 0; row < 32; ++row) {
        if (tid < 250)
            hs[row][tid] = h[((size_t)(b * DD + i0 + row)) * TT + tc * 250 + tid];
    }
    if (blockIdx.x == 0 && blockIdx.y == 0 && tid < 8)
        att0[b * 8 + tid] = expf(sc[(size_t)(b * 8 + tid) * 1024] - mrow[tid]) * invrow[tid];
    __syncthreads();
    int hh = tid >> 5, il = tid & 31;
    const float* arow = as[hh];
    const float* hrow = hs[il];
    float a0 = 0.f, a1 = 0.f;
#pragma unroll 5
    for (int u = 0; u < 250; u += 2) {
        a0 = fmaf(arow[u], hrow[u], a0);
        a1 = fmaf(arow[u + 1], hrow[u + 1], a1);
    }
    ctx1[(((size_t)tc * BB + b) * 8 + hh) * DD + i0 + il] = a0 + a1;
}

// ============ head: reduce ctx partials + cls term, then MLP ============
__global__ __launch_bounds__(256) void k_head(const float* __restrict__ ctx1,
                                              const float* __restrict__ att0,
                                              const float* __restrict__ cls,
                                              const float* __restrict__ inw,
                                              const float* __restrict__ inb, const float* __restrict__ outw,
                                              const float* __restrict__ outb, const float* __restrict__ w1,
                                              const float* __restrict__ b1, const float* __restrict__ w2,
                                              const float* __restrict__ b2, float* __restrict__ out) {
    int b = blockIdx.x;
    __shared__ float cs[2048], ao[256], po[256], hid[128];
    int j = threadIdx.x;
    {
        float cv = cls[j];
#pragma unroll
        for (int hh = 0; hh < 8; ++hh) {
            float a = att0[b * 8 + hh] * cv;
#pragma unroll
            for (int tc = 0; tc < 4; ++tc)
                a += ctx1[(((size_t)tc * BB + b) * 8 + hh) * DD + j];
            cs[hh * 256 + j] = a;
        }
    }
    __syncthreads();
    {
        int hh = j >> 5;
        float a = inb[2 * DD + j];
        const float* wv = inw + (size_t)(2 * DD + j) * DD;
        for (int i = 0; i < 256; ++i) a = fmaf(wv[i], cs[hh * 256 + i], a);
        ao[j] = a;
    }
    __syncthreads();
    {
        float a = outb[j];
        for (int i = 0; i < 256; ++i) a = fmaf(outw[j * DD + i], ao[i], a);
        po[j] = a;
    }
    __syncthreads();
    if (j < 128) {
        float a = b1[j];
        for (int i = 0; i < 256; ++i) a = fmaf(w1[j * 256 + i], po[i], a);
        hid[j] = fmaxf(a, 0.f);
    }
    __syncthreads();
    if (j == 0) {
        float a = b2[0];
        for (int i = 0; i < 128; ++i) a = fmaf(w2[i], hid[i], a);
        out[b] = a;
    }
}

extern "C" void kernel_launch(void* const* d_in, const int* in_sizes, int n_in,
                              void* d_out, int out_size, void* d_ws, size_t ws_size,
                              hipStream_t stream) {
    (void)in_sizes; (void)n_in; (void)out_size; (void)ws_size;
    const float* x        = (const float*)d_in[0];
    const float* w_in     = (const float*)d_in[1];
    const float* b_in     = (const float*)d_in[2];
    const float* ln_in_g  = (const float*)d_in[3];
    const float* ln_in_b  = (const float*)d_in[4];
    const float* s4B      = (const float*)d_in[5];
    const float* s4C      = (const float*)d_in[6];
    const float* s4logdt  = (const float*)d_in[7];
    const float* s4D      = (const float*)d_in[8];
    const float* ln_g     = (const float*)d_in[9];
    const float* ln_b     = (const float*)d_in[10];
    const float* cls      = (const float*)d_in[11];
    const float* mha_in_w = (const float*)d_in[12];
    const float* mha_in_b = (const float*)d_in[13];
    const float* mha_out_w= (const float*)d_in[14];
    const float* mha_out_b= (const float*)d_in[15];
    const float* head_w1  = (const float*)d_in[16];
    const float* head_b1  = (const float*)d_in[17];
    const float* head_w2  = (const float*)d_in[18];
    const float* head_b2  = (const float*)d_in[19];

    float* ws   = (float*)d_ws;
    float* h    = ws + OFF_H;
    float* kker = ws + OFF_K;
    float* invn = ws + OFF_INV;
    float* P  = ws + OFF_P;        // 33 * 4096 (outside h region)
    float* Q  = ws + OFF_Q;        // 32 * 4096
    float* Lb = ws + OFF_L;        // 4*256*32*64
    float* Rb = ws + OFF_R;        // 4*256*32*64
    float* qkb  = ws + OFF_MHA;
    float* qbb  = qkb + 2048;
    float* scb  = qbb + 16;        // reused: whi/wlo (pre-embed), then sc (scores)
    float* ctx1b = scb + 262144;
    float* att0 = ws + OFF_K + 1024000;  // gap between kker end (9216000) and invn (9232384)
    unsigned short* whi = (unsigned short*)scb;
    unsigned short* wlo = whi + 256 * 136;

    k_build_ad<<<dim3(258), dim3(256), 0, stream>>>(s4logdt, P, w_in, whi, wlo,
                                                    cls, mha_in_w, mha_in_b, qkb, qbb);
    k_pe<<<dim3(62 + 512), dim3(512), 0, stream>>>(P, Q, x, whi, wlo, w_in, b_in,
                                                   ln_in_g, ln_in_b, h, invn);
    k_lr<<<dim3(NLY * 64), dim3(256), 0, stream>>>(P, Q, s4B, s4C, Lb, Rb);
    k_kker<<<dim3(NLY * 256), dim3(256), 0, stream>>>(Lb, Rb, kker);

    for (int l = 0; l < NLY; ++l) {
        k_conv32<<<dim3(DD, 4), dim3(512), 0, stream>>>(h, kker, invn, s4D, l);
        k_ln<<<dim3(16, BB), dim3(256), 0, stream>>>(h, ln_g + l * DD, ln_b + l * DD, h, invn);
    }

    k_scores<<<dim3(8, BB), dim3(128), 0, stream>>>(h, cls, qkb, qbb, scb);
    k_ctx1<<<dim3(8, 4, BB), dim3(256), 0, stream>>>(h, scb, ctx1b, att0);
    k_head<<<dim3(BB), dim3(256), 0, stream>>>(ctx1b, att0, cls, mha_in_w, mha_in_b,
                                               mha_out_w, mha_out_b,
                                               head_w1, head_b1, head_w2, head_b2, (float*)d_out);
}

// Round 17
// 462.040 us; speedup vs baseline: 1.2700x; 1.2700x over previous
//
#include <hip/hip_runtime.h>

#define BB 32
#define CC 129
#define TT 1000
#define DD 256
#define NN 64
#define NLY 4

// ---------------- workspace layout (floats) ----------------
// h occupies [0, 8192000). P/Q/L/R live OUT of h so the powers chain can run
// CONCURRENTLY with embed (which writes all of h).
#define OFF_H    0
#define OFF_K    8192000
#define OFF_INV  9232384
#define OFF_MHA  9264384
#define OFF_P    10000000
#define OFF_Q    10140000
#define OFF_L    10280000
#define OFF_R    12380000

typedef __attribute__((ext_vector_type(8))) short bf16x8;
typedef __attribute__((ext_vector_type(8))) _Float16 f16x8;
typedef __attribute__((ext_vector_type(4))) float f32x4;
typedef __attribute__((ext_vector_type(16))) float f32x16;

__device__ __forceinline__ unsigned short f2bf(float x) {
    unsigned int u = __float_as_uint(x);
    unsigned int r = (u + 0x7FFF + ((u >> 16) & 1)) >> 16;
    return (unsigned short)r;
}
__device__ __forceinline__ float bf2f(unsigned short b) {
    return __uint_as_float(((unsigned int)b) << 16);
}
__device__ __forceinline__ unsigned short f2h(float x) {
    _Float16 v = (_Float16)x;
    return *(unsigned short*)&v;
}
__device__ __forceinline__ float h2f(unsigned short b) {
    _Float16 v = *(_Float16*)&b;
    return (float)v;
}

// ============ Ad build (block 0) + w_in prep (1..256) + MHA qprep (257) ============
// Sherman-Morrison + Newton polish (HW-verified R4/R7/R8/R10-R14). qprep as block 257.
#define BST 68
__global__ __launch_bounds__(256, 1) void k_build_ad(const float* __restrict__ logdt,
                                                     float* __restrict__ P,
                                                     const float* __restrict__ w_in,
                                                     unsigned short* __restrict__ whi,
                                                     unsigned short* __restrict__ wlo,
                                                     const float* __restrict__ cls,
                                                     const float* __restrict__ inw,
                                                     const float* __restrict__ inb,
                                                     float* __restrict__ qk,
                                                     float* __restrict__ qb) {
    int tid = threadIdx.x;
    if (blockIdx.x == 257) {           // ---- qprep path ----
        __shared__ float Qv[256];
        int j = tid;
        float a = inb[j];
        for (int i = 0; i < 256; ++i) a = fmaf(inw[j * DD + i], cls[i], a);
        Qv[j] = a;
        __syncthreads();
        const float scale = 0.17677669529663687f; // 1/sqrt(32)
        for (int idx = tid; idx < 8 * 256; idx += 256) {
            int hh = idx >> 8, i = idx & 255;
            float s = 0.f;
            for (int jj = 0; jj < 32; ++jj)
                s = fmaf(Qv[hh * 32 + jj], inw[(DD + hh * 32 + jj) * DD + i], s);
            qk[idx] = s * scale;
        }
        if (tid < 8) {
            int hh = tid;
            float s = 0.f;
            for (int jj = 0; jj < 32; ++jj)
                s = fmaf(Qv[hh * 32 + jj], inb[DD + hh * 32 + jj], s);
            qb[hh] = s * scale;
        }
        return;
    }
    if (blockIdx.x != 0) {             // ---- w_in split-bf16 prep ----
        int d = blockIdx.x - 1;      // 0..255
        int c = tid;
        if (c < 136) {
            float v = (c < CC) ? w_in[d * CC + c] : 0.f;
            unsigned short h = f2bf(v);
            whi[d * 136 + c] = h;
            wlo[d * 136 + c] = f2bf(v - bf2f(h));
        }
        return;
    }
    __shared__ __align__(16) float Ms[64 * BST];
    __shared__ __align__(16) float Vs[64 * BST];
    __shared__ __align__(16) float Ws[64 * BST];
    float dt = expf(logdt[0]);
    dt = fminf(fmaxf(dt, 1e-4f), 0.1f);
    float hh = dt * 0.5f;
    int w = tid >> 6, r = tid & 63;
    {
        float Pr = sqrtf(1.f + 2.f * (float)r);
#pragma unroll
        for (int jj = 0; jj < 16; ++jj) {
            int j = w * 16 + jj;
            float av;
            if (r == j) av = -((float)r + 0.5f);
            else { float m = Pr * sqrtf(1.f + 2.f * (float)j); av = (r > j) ? -m : m; }
            Ms[r * BST + j] = ((r == j) ? 1.f : 0.f) - hh * av;
        }
    }
    if (tid < 64) {
        int lane = tid;
        float x[64], u[64];
        float s = 0.f, su = 0.f;
#pragma unroll
        for (int i = 0; i < 64; ++i) {
            const float Pi = sqrtf(2.f * (float)i + 1.f);
            float Lii = fmaf(3.f * ((float)i + 0.5f), hh, 1.f);
            float rinv = 1.f / Lii;
            float c = 2.f * hh * Pi;
            float del = (lane == i) ? 1.f : 0.f;
            x[i] = (del - c * s) * rinv;
            s = fmaf(Pi, x[i], s);
            u[i] = (Pi - c * su) * rinv;
            su = fmaf(Pi, u[i], su);
        }
        float beta = hh / (1.f - hh * su);
        float bv = beta * s;
#pragma unroll
        for (int i = 0; i < 64; ++i)
            Vs[i * BST + lane] = fmaf(bv, u[i], x[i]);
    }
    __syncthreads();
    // ---- Newton refine, step A: W = 2I - M*V ----
    {
        int tr = (tid >> 4) << 2, tc = (tid & 15) << 2;
        float acc[4][4];
#pragma unroll
        for (int u = 0; u < 4; ++u)
#pragma unroll
            for (int v = 0; v < 4; ++v) acc[u][v] = 0.f;
        for (int k0 = 0; k0 < 64; k0 += 4) {
            f32x4 av[4], bv[4];
#pragma unroll
            for (int u = 0; u < 4; ++u) av[u] = *(const f32x4*)&Ms[(tr + u) * BST + k0];
#pragma unroll
            for (int kk = 0; kk < 4; ++kk) bv[kk] = *(const f32x4*)&Vs[(k0 + kk) * BST + tc];
#pragma unroll
            for (int u = 0; u < 4; ++u)
#pragma unroll
                for (int kk = 0; kk < 4; ++kk)
#pragma unroll
                    for (int v = 0; v < 4; ++v)
                        acc[u][v] = fmaf(av[u][kk], bv[kk][v], acc[u][v]);
        }
        __syncthreads();
#pragma unroll
        for (int u = 0; u < 4; ++u)
#pragma unroll
            for (int v = 0; v < 4; ++v)
                Ws[(tr + u) * BST + tc + v] =
                    (((tr + u) == (tc + v)) ? 2.f : 0.f) - acc[u][v];
    }
    __syncthreads();
    // ---- Newton refine, step B: Ad = 2*(V*W) - I ; also P[0] = I ----
    {
        int tr = (tid >> 4) << 2, tc = (tid & 15) << 2;
        float acc[4][4];
#pragma unroll
        for (int u = 0; u < 4; ++u)
#pragma unroll
            for (int v = 0; v < 4; ++v) acc[u][v] = 0.f;
        for (int k0 = 0; k0 < 64; k0 += 4) {
            f32x4 av[4], bv[4];
#pragma unroll
            for (int u = 0; u < 4; ++u) av[u] = *(const f32x4*)&Vs[(tr + u) * BST + k0];
#pragma unroll
            for (int kk = 0; kk < 4; ++kk) bv[kk] = *(const f32x4*)&Ws[(k0 + kk) * BST + tc];
#pragma unroll
            for (int u = 0; u < 4; ++u)
#pragma unroll
                for (int kk = 0; kk < 4; ++kk)
#pragma unroll
                    for (int v = 0; v < 4; ++v)
                        acc[u][v] = fmaf(av[u][kk], bv[kk][v], acc[u][v]);
        }
#pragma unroll
        for (int u = 0; u < 4; ++u)
#pragma unroll
            for (int v = 0; v < 4; ++v) {
                int rr = tr + u, cc = tc + v;
                float eye = (rr == cc) ? 1.f : 0.f;
                P[rr * 64 + cc] = eye;
                P[4096 + rr * 64 + cc] = 2.f * acc[u][v] - eye;
            }
    }
}

// ============ mm64x / powm (512-thread, HW-verified R10-R14) ============
#define PLDA 68
__device__ __forceinline__ void mm64x(float* D, const float* A, const float* B) {
    int tr = (threadIdx.x >> 4) << 1, tc = (threadIdx.x & 15) << 2;
    float acc[2][4];
#pragma unroll
    for (int u = 0; u < 2; ++u)
#pragma unroll
        for (int v = 0; v < 4; ++v) acc[u][v] = 0.f;
#pragma unroll 2
    for (int k0 = 0; k0 < 64; k0 += 4) {
        f32x4 av[2], bv[4];
#pragma unroll
        for (int u = 0; u < 2; ++u) av[u] = *(const f32x4*)&A[(tr + u) * PLDA + k0];
#pragma unroll
        for (int kk = 0; kk < 4; ++kk) bv[kk] = *(const f32x4*)&B[(k0 + kk) * PLDA + tc];
#pragma unroll
        for (int u = 0; u < 2; ++u)
#pragma unroll
            for (int kk = 0; kk < 4; ++kk)
#pragma unroll
                for (int v = 0; v < 4; ++v)
                    acc[u][v] = fmaf(av[u][kk], bv[kk][v], acc[u][v]);
    }
    __syncthreads();
#pragma unroll
    for (int u = 0; u < 2; ++u)
#pragma unroll
        for (int v = 0; v < 4; ++v) D[(tr + u) * PLDA + tc + v] = acc[u][v];
    __syncthreads();
}

__device__ float* powm(float* U, float* V, const float* base, int e) {
    for (int i = threadIdx.x; i < 4096; i += 512)
        U[(i >> 6) * PLDA + (i & 63)] = base[(i >> 6) * PLDA + (i & 63)];
    __syncthreads();
    float* X = U; float* Y = V;
    for (int bit = 30 - __builtin_clz(e); bit >= 0; --bit) {
        mm64x(Y, X, X); { float* t = X; X = Y; Y = t; }
        if ((e >> bit) & 1) { mm64x(Y, X, base); float* t = X; X = Y; Y = t; }
    }
    return X;
}

// ============ MERGED powers (blocks 0-61) + embed (blocks 62-573) ============
// LDS 52224 B (AdS-reuse eliminates BaseS; bitwise-identical P/Q). Duration is
// bounded by the powers serial chain (occupancy-invariant per R13/R14 A/B) — left as-is.
__global__ __launch_bounds__(512, 4) void k_pe(float* __restrict__ P, float* __restrict__ Q,
                                               const float* __restrict__ x,
                                               const unsigned short* __restrict__ whi,
                                               const unsigned short* __restrict__ wlo,
                                               const float* __restrict__ w_in,
                                               const float* __restrict__ b_in,
                                               const float* __restrict__ lng,
                                               const float* __restrict__ lnb,
                                               float* __restrict__ h,
                                               float* __restrict__ invn) {
    __shared__ __align__(16) char smem[52224];
    int tid = threadIdx.x;
    if (blockIdx.x < 62) {
        // ---- powers path (3 LDS buffers: AdS, Ub, Vb) ----
        float* AdS = (float*)smem;
        float* Ub  = AdS + 64 * PLDA;
        float* Vb  = Ub + 64 * PLDA;
        int bid = blockIdx.x;
        if (bid == 61) {   // Q[0] = I
            for (int i = tid; i < 4096; i += 512) Q[i] = ((i >> 6) == (i & 63)) ? 1.f : 0.f;
            return;
        }
        const float* Ad = P + 4096;
        for (int i = tid; i < 4096; i += 512) AdS[(i >> 6) * PLDA + (i & 63)] = Ad[i];
        __syncthreads();
        float* res;
        float* out;
        if (bid < 30) {                    // P[2+bid] = Ad^(2+bid)
            res = powm(Ub, Vb, AdS, bid + 2);
            out = P + (size_t)(bid + 2) * 4096;
        } else {                           // Q[i] = (Ad^32)^i, i = bid-29 in 1..31
            int iq = bid - 29;
            float* b32 = powm(Ub, Vb, AdS, 32);
            // AdS (the Ad copy) is dead now; reuse it as the base-32 buffer.
            for (int i = tid; i < 4096; i += 512)
                AdS[(i >> 6) * PLDA + (i & 63)] = b32[(i >> 6) * PLDA + (i & 63)];
            __syncthreads();
            res = powm(Ub, Vb, AdS, iq);
            out = Q + (size_t)iq * 4096;
        }
        for (int i = tid; i < 4096; i += 512) out[i] = res[(i >> 6) * PLDA + (i & 63)];
        return;
    }
    // ---- embed path (verbatim R10-R14 body; LDS via smem overlay, 42240 B) ----
    unsigned short* xs_h = (unsigned short*)smem;
    unsigned short* xs_l = (unsigned short*)(smem + 16640);
    float* xlasts = (float*)(smem + 33280);
    float* w128s  = (float*)(smem + 33536);
    float* biass  = (float*)(smem + 34560);
    float* gs     = (float*)(smem + 35584);
    float* bs     = (float*)(smem + 36608);
    float (*ps)[8]  = (float(*)[8])(smem + 37632);
    float (*ps2)[8] = (float(*)[8])(smem + 39680);
    float* mstat  = (float*)(smem + 41728);
    float* rstat  = (float*)(smem + 41984);
    int e = blockIdx.x - 62;
    int b = e >> 4, t0 = (e & 15) * 64;
    for (int i = tid; i < CC * 64; i += 512) {
        int c = i >> 6, tl = i & 63;
        int t = t0 + tl;
        float v = (t < TT) ? x[(size_t)(b * CC + c) * TT + t] : 0.f;
        if (c == 128) {
            xlasts[tl] = v;
        } else {
            unsigned short hh = f2bf(v);
            xs_h[tl * 130 + c] = hh;
            xs_l[tl * 130 + c] = f2bf(v - bf2f(hh));
        }
    }
    if (tid < 256) {
        w128s[tid] = w_in[tid * CC + 128];
        biass[tid] = b_in[tid];
        gs[tid] = lng[tid];
        bs[tid] = lnb[tid];
    }
    __syncthreads();
    int wave = tid >> 6, lane = tid & 63;
    int tn = lane & 15, q = lane >> 4;
    int d0w = wave * 32;
    f32x4 acc[4][2];
#pragma unroll
    for (int nt = 0; nt < 4; ++nt)
#pragma unroll
        for (int mt = 0; mt < 2; ++mt) acc[nt][mt] = (f32x4){0.f, 0.f, 0.f, 0.f};
#pragma unroll
    for (int kc = 0; kc < 4; ++kc) {
        int c0 = kc * 32;
        bf16x8 Ah[2], Al[2];
#pragma unroll
        for (int mt = 0; mt < 2; ++mt) {
            int base = (d0w + mt * 16 + tn) * 136 + c0 + 8 * q;
            Ah[mt] = *(const bf16x8*)&whi[base];
            Al[mt] = *(const bf16x8*)&wlo[base];
        }
#pragma unroll
        for (int nt = 0; nt < 4; ++nt) {
            const unsigned int* ph = (const unsigned int*)&xs_h[(nt * 16 + tn) * 130 + c0 + 8 * q];
            const unsigned int* pl = (const unsigned int*)&xs_l[(nt * 16 + tn) * 130 + c0 + 8 * q];
            union { bf16x8 v; unsigned int u[4]; } Bh, Bl;
            Bh.u[0] = ph[0]; Bh.u[1] = ph[1]; Bh.u[2] = ph[2]; Bh.u[3] = ph[3];
            Bl.u[0] = pl[0]; Bl.u[1] = pl[1]; Bl.u[2] = pl[2]; Bl.u[3] = pl[3];
#pragma unroll
            for (int mt = 0; mt < 2; ++mt) {
                acc[nt][mt] = __builtin_amdgcn_mfma_f32_16x16x32_bf16(Al[mt], Bh.v, acc[nt][mt], 0, 0, 0);
                acc[nt][mt] = __builtin_amdgcn_mfma_f32_16x16x32_bf16(Ah[mt], Bl.v, acc[nt][mt], 0, 0, 0);
                acc[nt][mt] = __builtin_amdgcn_mfma_f32_16x16x32_bf16(Ah[mt], Bh.v, acc[nt][mt], 0, 0, 0);
            }
        }
    }
#pragma unroll
    for (int nt = 0; nt < 4; ++nt) {
        float xl = xlasts[nt * 16 + tn];
        float s = 0.f, s2 = 0.f;
#pragma unroll
        for (int mt = 0; mt < 2; ++mt) {
#pragma unroll
            for (int r = 0; r < 4; ++r) {
                int d = d0w + mt * 16 + 4 * q + r;
                float v = acc[nt][mt][r] + biass[d] + w128s[d] * xl;
                acc[nt][mt][r] = v;
                s += v; s2 = fmaf(v, v, s2);
            }
        }
        s += __shfl_xor(s, 16); s += __shfl_xor(s, 32);
        s2 += __shfl_xor(s2, 16); s2 += __shfl_xor(s2, 32);
        if (q == 0) { ps[nt * 16 + tn][wave] = s; ps2[nt * 16 + tn][wave] = s2; }
    }
    __syncthreads();
    if (tid < 64) {
        float s = 0.f, s2 = 0.f;
#pragma unroll
        for (int k = 0; k < 8; ++k) { s += ps[tid][k]; s2 += ps2[tid][k]; }
        float mean = s * (1.f / 256.f);
        float ex2 = s2 * (1.f / 256.f);
        mstat[tid] = mean;
        rstat[tid] = 1.f / sqrtf(ex2 - mean * mean + 1e-5f);
    }
    __syncthreads();
    float sq[4] = {0.f, 0.f, 0.f, 0.f};
#pragma unroll
    for (int mt = 0; mt < 2; ++mt) {
#pragma unroll
        for (int r = 0; r < 4; ++r) {
            int d = d0w + mt * 16 + 4 * q + r;
            float gd = gs[d], bd = bs[d];
            float freq = expf((float)(d & ~1) * (-9.210340371976184f / 256.f));
            int odd = d & 1;
#pragma unroll
            for (int nt = 0; nt < 4; ++nt) {
                int tl = nt * 16 + tn;
                int t = t0 + tl;
                float o = (acc[nt][mt][r] - mstat[tl]) * rstat[tl] * gd + bd;
                float ang = (float)t * freq;
                o += odd ? cosf(ang) : sinf(ang);
                if (t < TT) h[((size_t)(b * DD + d)) * TT + t] = o;
                sq[nt] = fmaf(o, o, sq[nt]);
            }
        }
    }
#pragma unroll
    for (int nt = 0; nt < 4; ++nt) {
        float s = sq[nt];
        s += __shfl_xor(s, 16); s += __shfl_xor(s, 32);
        if (q == 0) ps[nt * 16 + tn][wave] = s;
    }
    __syncthreads();
    if (tid < 64) {
        int t = t0 + tid;
        if (t < TT) {
            float s = 0.f;
#pragma unroll
            for (int k = 0; k < 8; ++k) s += ps[tid][k];
            invn[b * TT + t] = 1.f / (sqrtf(s) + 1e-8f);
        }
    }
}

// ============ L / R ============
__global__ __launch_bounds__(256) void k_lr(const float* __restrict__ P, const float* __restrict__ Q,
                                            const float* __restrict__ s4B, const float* __restrict__ s4C,
                                            float* __restrict__ L, float* __restrict__ R) {
    __shared__ float Ms[4096];
    int l = blockIdx.x >> 6, rem = blockIdx.x & 63, which = rem >> 5, idx = rem & 31;
    const float* M = which ? (P + (size_t)idx * 4096)
                           : (Q + (size_t)idx * 4096);
    for (int i = threadIdx.x; i < 4096; i += 256) Ms[i] = M[i];
    __syncthreads();
    int d = threadIdx.x;
    if (which == 0) {
        float* dst = L + (((size_t)(l * DD + d) * 32 + idx) * 64);
        for (int jc = 0; jc < 8; ++jc) {
            float acc[8];
#pragma unroll
            for (int u = 0; u < 8; ++u) acc[u] = 0.f;
            for (int i = 0; i < 64; ++i) {
                float bv = s4B[(l * NN + i) * DD + d];
#pragma unroll
                for (int u = 0; u < 8; ++u)
                    acc[u] = fmaf(bv, Ms[i * 64 + jc * 8 + u], acc[u]);
            }
#pragma unroll
            for (int u = 0; u < 8; ++u) dst[jc * 8 + u] = acc[u];
        }
    } else {
        float* dst = R + (((size_t)(l * DD + d) * 32 + idx) * 64);
        const float* Cp = s4C + (size_t)(l * DD + d) * NN;
        for (int ic = 0; ic < 8; ++ic) {
            float acc[8];
#pragma unroll
            for (int u = 0; u < 8; ++u) acc[u] = 0.f;
            for (int j = 0; j < 64; ++j) {
                float cv = Cp[j];
#pragma unroll
                for (int u = 0; u < 8; ++u)
                    acc[u] = fmaf(Ms[(ic * 8 + u) * 64 + j], cv, acc[u]);
            }
#pragma unroll
            for (int u = 0; u < 8; ++u) dst[ic * 8 + u] = acc[u];
        }
    }
}

// ============ kernel assembly ============
__global__ __launch_bounds__(256) void k_kker(const float* __restrict__ L, const float* __restrict__ R,
                                              float* __restrict__ kk) {
    __shared__ float Ls[32 * 65], Rs[32 * 65];
    int l = blockIdx.x >> 8, d = blockIdx.x & 255;
    const float* Lp = L + ((size_t)(l * DD + d) * 32) * 64;
    const float* Rp = R + ((size_t)(l * DD + d) * 32) * 64;
    for (int i = threadIdx.x; i < 2048; i += 256) {
        int row = i >> 6, col = i & 63;
        Ls[row * 65 + col] = Lp[i];
        Rs[row * 65 + col] = Rp[i];
    }
    __syncthreads();
    for (int t = threadIdx.x; t < TT; t += 256) {
        int kq = t >> 5, r = t & 31;
        const float* lr = &Ls[kq * 65];
        const float* rr = &Rs[r * 65];
        float a = 0.f;
#pragma unroll 8
        for (int m = 0; m < 64; ++m) a = fmaf(lr[m], rr[m], a);
        kk[(size_t)(l * DD + d) * TT + t] = a * expf(-0.01f * (float)t);
    }
}

// ============ LayerNorm (in-place), single-pass ============
__global__ __launch_bounds__(256) void k_ln(const float* __restrict__ in, const float* __restrict__ g,
                                            const float* __restrict__ bia, float* __restrict__ out,
                                            float* __restrict__ invn) {
    int b = blockIdx.y, t0 = blockIdx.x * 64;
    int w = threadIdx.x >> 6, lane = threadIdx.x & 63;
    int t = t0 + lane;
    __shared__ float ps[4][64], ps2[4][64];
    float v[64];
    float s = 0.f, s2 = 0.f;
    bool ok = t < TT;
#pragma unroll
    for (int k = 0; k < 64; ++k) {
        float x = ok ? in[(size_t)(b * DD + (w + 4 * k)) * TT + t] : 0.f;
        v[k] = x;
        s += x; s2 = fmaf(x, x, s2);
    }
    ps[w][lane] = s; ps2[w][lane] = s2;
    __syncthreads();
    float mean = (ps[0][lane] + ps[1][lane] + ps[2][lane] + ps[3][lane]) * (1.f / 256.f);
    float ex2  = (ps2[0][lane] + ps2[1][lane] + ps2[2][lane] + ps2[3][lane]) * (1.f / 256.f);
    float rstd = 1.f / sqrtf(ex2 - mean * mean + 1e-5f);
    float sq = 0.f;
    if (ok) {
#pragma unroll
        for (int k = 0; k < 64; ++k) {
            int d = w + 4 * k;
            float o = (v[k] - mean) * rstd * g[d] + bia[d];
            out[(size_t)(b * DD + d) * TT + t] = o;
            sq = fmaf(o, o, sq);
        }
    }
    __syncthreads();
    ps[w][lane] = sq;
    __syncthreads();
    if (w == 0 && ok) {
        float tot = ps[0][lane] + ps[1][lane] + ps[2][lane] + ps[3][lane];
        invn[b * TT + t] = 1.f / (sqrtf(tot) + 1e-8f);
    }
}

__device__ __forceinline__ float gelu_exact(float y) {
    return 0.5f * y * (1.f + erff(y * 0.7071067811865476f));
}

// ============ MFMA conv v3 (HW-verified R8/R10-R14): safe 16-batch split, grid (DD, 2) ============
// v4 (8-batch, grid (DD,4)) REGRESSED +117us in R15: 4x replicated pks/kk staging
// + scattered 8-row epilogues thrash L2. 16-batch is the measured optimum.
#define XS2 1032
__global__ __launch_bounds__(512) void k_conv32(float* __restrict__ h, const float* __restrict__ kk,
                                                const float* __restrict__ invn,
                                                const float* __restrict__ s4D, int layer) {
    __shared__ unsigned short Xs[16 * XS2];
    __shared__ unsigned int pks[1056];
    int d = blockIdx.x;
    int bbase = blockIdx.y * 16;
    int tid = threadIdx.x;
    const float* krow = kk + (size_t)(layer * DD + d) * TT;
    for (int mm = tid; mm < 1056; mm += 512) {
        int m = mm - 32;
        float klo = (m >= 0 && m < TT) ? krow[m] : 0.f;
        float kpr = (m >= 1 && m <= TT) ? krow[m - 1] : 0.f;
        pks[mm] = (unsigned int)f2h(klo) | ((unsigned int)f2h(kpr) << 16);
    }
    for (int ii = tid; ii < 16 * 512; ii += 512) {
        int bb = ii >> 9;                       // 0..15 local batch
        int tp = (ii & 511) * 2;
        const float* hrow = h + ((size_t)(bbase + bb) * DD + d) * TT;
        const float* ivr = invn + (size_t)(bbase + bb) * TT;
        float v0 = (tp < TT) ? hrow[tp] * ivr[tp] : 0.f;
        float v1 = (tp + 1 < TT) ? hrow[tp + 1] * ivr[tp + 1] : 0.f;
        ((unsigned int*)Xs)[(bb * XS2 + tp) >> 1] = (unsigned int)f2h(v0) | ((unsigned int)f2h(v1) << 16);
    }
    __syncthreads();
    float gate = 1.f / (1.f + expf(-s4D[layer * DD + d]));
    int wave = tid >> 6, lane = tid & 63;
    int nn = lane & 31, kq8 = (lane >> 5) << 3;
    int bp = nn & 15;                           // A-row batch (rows 16-31 duplicate 0-15)
    for (int pass = 0; pass < 2; ++pass) {
        int G = pass ? (15 - wave) : wave;
        int jlo = 2 * G;
        f32x16 acc[2];
#pragma unroll
        for (int m = 0; m < 2; ++m)
#pragma unroll
            for (int r = 0; r < 16; ++r) acc[m][r] = 0.f;
        for (int D = 32 * jlo + 32; D >= -16; D -= 16) {
            int S32 = D + nn - kq8 + 32;
            union { f16x8 v; unsigned int u[4]; } bh;
            bh.u[0] = pks[S32];
            bh.u[1] = pks[S32 - 2];
            bh.u[2] = pks[S32 - 4];
            bh.u[3] = pks[S32 - 6];
#pragma unroll
            for (int m = 0; m < 2; ++m) {
                int u0 = (jlo + m) * 32 - D;
                if (u0 >= 0) {
                    const f16x8 ah = *(const f16x8*)&Xs[bp * XS2 + u0 + kq8];
                    acc[m] = __builtin_amdgcn_mfma_f32_32x32x16_f16(ah, bh.v, acc[m], 0, 0, 0);
                }
            }
        }
#pragma unroll
        for (int m = 0; m < 2; ++m) {
            int t = (jlo + m) * 32 + nn;
            if (t < TT) {
#pragma unroll
                for (int r = 0; r < 16; ++r) {
                    int brow = (r & 3) + 8 * (r >> 2) + 4 * (lane >> 5);
                    if (brow < 16) {            // rows 16-31 are discarded duplicates
                        size_t ix = ((size_t)(bbase + brow) * DD + d) * TT + t;
                        float y = acc[m][r];
                        float xn = h2f(Xs[brow * XS2 + t]);
                        float ho = h[ix];       // L2-hot re-read (exact residual)
                        h[ix] = gelu_exact(y + xn * gate) + 1.1f * ho;
                    }
                }
            }
        }
    }
}

// ============ MHA scores ============
__global__ __launch_bounds__(128) void k_scores(const float* __restrict__ h, const float* __restrict__ cls,
                                                const float* __restrict__ qkw, const float* __restrict__ qbw,
                                                float* __restrict__ sc) {
    __shared__ float qks[8 * 256];
    int b = blockIdx.y;
    int s = blockIdx.x * 128 + threadIdx.x;
    for (int i = threadIdx.x; i < 2048; i += 128) qks[i] = qkw[i];
    __syncthreads();
    if (s >= TT + 1) return;
    float acc[8];
#pragma unroll
    for (int hh = 0; hh < 8; ++hh) acc[hh] = qbw[hh];
    if (s == 0) {
        for (int i = 0; i < 256; ++i) {
            float v = cls[i];
#pragma unroll
            for (int hh = 0; hh < 8; ++hh) acc[hh] = fmaf(qks[hh * 256 + i], v, acc[hh]);
        }
    } else {
        const float* hb = h + (size_t)b * DD * TT + (s - 1);
        for (int i = 0; i < 256; ++i) {
            float v = hb[(size_t)i * TT];
#pragma unroll
            for (int hh = 0; hh < 8; ++hh) acc[hh] = fmaf(qks[hh * 256 + i], v, acc[hh]);
        }
    }
#pragma unroll
    for (int hh = 0; hh < 8; ++hh) sc[(size_t)(b * 8 + hh) * 1024 + s] = acc[hh];
}

// ============ ctx stage 1 with FUSED softmax, shuffle-free (HW-verified R12-R14) ============
__global__ __launch_bounds__(256) void k_ctx1(const float* __restrict__ h,
                                              const float* __restrict__ sc,
                                              float* __restrict__ ctx1,
                                              float* __restrict__ att0) {
    __shared__ float as[8][256];
    __shared__ float hs[32][251];
    __shared__ float mrow[8], invrow[8];
    int i0 = blockIdx.x * 32, tc = blockIdx.y, b = blockIdx.z;
    int tid = threadIdx.x;
    {
        int hh = tid >> 5, l32 = tid & 31;
        const float* p = sc + (size_t)(b * 8 + hh) * 1024;
        float m = -3.4e38f;
        for (int s = l32; s < TT + 1; s += 32) m = fmaxf(m, p[s]);
#pragma unroll
        for (int off = 16; off; off >>= 1) m = fmaxf(m, __shfl_xor(m, off, 32));
        float sum = 0.f;
        for (int s = l32; s < TT + 1; s += 32) sum += expf(p[s] - m);
#pragma unroll
        for (int off = 16; off; off >>= 1) sum += __shfl_xor(sum, off, 32);
        if (l32 == 0) { mrow[hh] = m; invrow[hh] = 1.f / sum; }
    }
    __syncthreads();
    int sbase = tc * 250 + 1;
    for (int idx = tid; idx < 2048; idx += 256) {
        int hh = idx >> 8, u = idx & 255;
        as[hh][u] = (u < 250)
            ? expf(sc[(size_t)(b * 8 + hh) * 1024 + sbase + u] - mrow[hh]) * invrow[hh]
            : 0.f;
    }
    // stage h tile [32 i][250 t], coalesced one row per iteration
    for (int row = 0; row < 32; ++row) {
        if (tid < 250)
            hs[row][tid] = h[((size_t)(b * DD + i0 + row)) * TT + tc * 250 + tid];
    }
    if (blockIdx.x == 0 && blockIdx.y == 0 && tid < 8)
        att0[b * 8 + tid] = expf(sc[(size_t)(b * 8 + tid) * 1024] - mrow[tid]) * invrow[tid];
    __syncthreads();
    int hh = tid >> 5, il = tid & 31;
    const float* arow = as[hh];
    const float* hrow = hs[il];
    float a0 = 0.f, a1 = 0.f;
#pragma unroll 5
    for (int u = 0; u < 250; u += 2) {
        a0 = fmaf(arow[u], hrow[u], a0);
        a1 = fmaf(arow[u + 1], hrow[u + 1], a1);
    }
    ctx1[(((size_t)tc * BB + b) * 8 + hh) * DD + i0 + il] = a0 + a1;
}

// ============ head: reduce ctx partials + cls term, then MLP ============
__global__ __launch_bounds__(256) void k_head(const float* __restrict__ ctx1,
                                              const float* __restrict__ att0,
                                              const float* __restrict__ cls,
                                              const float* __restrict__ inw,
                                              const float* __restrict__ inb, const float* __restrict__ outw,
                                              const float* __restrict__ outb, const float* __restrict__ w1,
                                              const float* __restrict__ b1, const float* __restrict__ w2,
                                              const float* __restrict__ b2, float* __restrict__ out) {
    int b = blockIdx.x;
    __shared__ float cs[2048], ao[256], po[256], hid[128];
    int j = threadIdx.x;
    {
        float cv = cls[j];
#pragma unroll
        for (int hh = 0; hh < 8; ++hh) {
            float a = att0[b * 8 + hh] * cv;
#pragma unroll
            for (int tc = 0; tc < 4; ++tc)
                a += ctx1[(((size_t)tc * BB + b) * 8 + hh) * DD + j];
            cs[hh * 256 + j] = a;
        }
    }
    __syncthreads();
    {
        int hh = j >> 5;
        float a = inb[2 * DD + j];
        const float* wv = inw + (size_t)(2 * DD + j) * DD;
        for (int i = 0; i < 256; ++i) a = fmaf(wv[i], cs[hh * 256 + i], a);
        ao[j] = a;
    }
    __syncthreads();
    {
        float a = outb[j];
        for (int i = 0; i < 256; ++i) a = fmaf(outw[j * DD + i], ao[i], a);
        po[j] = a;
    }
    __syncthreads();
    if (j < 128) {
        float a = b1[j];
        for (int i = 0; i < 256; ++i) a = fmaf(w1[j * 256 + i], po[i], a);
        hid[j] = fmaxf(a, 0.f);
    }
    __syncthreads();
    if (j == 0) {
        float a = b2[0];
        for (int i = 0; i < 128; ++i) a = fmaf(w2[i], hid[i], a);
        out[b] = a;
    }
}

extern "C" void kernel_launch(void* const* d_in, const int* in_sizes, int n_in,
                              void* d_out, int out_size, void* d_ws, size_t ws_size,
                              hipStream_t stream) {
    (void)in_sizes; (void)n_in; (void)out_size; (void)ws_size;
    const float* x        = (const float*)d_in[0];
    const float* w_in     = (const float*)d_in[1];
    const float* b_in     = (const float*)d_in[2];
    const float* ln_in_g  = (const float*)d_in[3];
    const float* ln_in_b  = (const float*)d_in[4];
    const float* s4B      = (const float*)d_in[5];
    const float* s4C      = (const float*)d_in[6];
    const float* s4logdt  = (const float*)d_in[7];
    const float* s4D      = (const float*)d_in[8];
    const float* ln_g     = (const float*)d_in[9];
    const float* ln_b     = (const float*)d_in[10];
    const float* cls      = (const float*)d_in[11];
    const float* mha_in_w = (const float*)d_in[12];
    const float* mha_in_b = (const float*)d_in[13];
    const float* mha_out_w= (const float*)d_in[14];
    const float* mha_out_b= (const float*)d_in[15];
    const float* head_w1  = (const float*)d_in[16];
    const float* head_b1  = (const float*)d_in[17];
    const float* head_w2  = (const float*)d_in[18];
    const float* head_b2  = (const float*)d_in[19];

    float* ws   = (float*)d_ws;
    float* h    = ws + OFF_H;
    float* kker = ws + OFF_K;
    float* invn = ws + OFF_INV;
    float* P  = ws + OFF_P;        // 33 * 4096 (outside h region)
    float* Q  = ws + OFF_Q;        // 32 * 4096
    float* Lb = ws + OFF_L;        // 4*256*32*64
    float* Rb = ws + OFF_R;        // 4*256*32*64
    float* qkb  = ws + OFF_MHA;
    float* qbb  = qkb + 2048;
    float* scb  = qbb + 16;        // reused: whi/wlo (pre-embed), then sc (scores)
    float* ctx1b = scb + 262144;
    float* att0 = ws + OFF_K + 1024000;  // gap between kker end (9216000) and invn (9232384)
    unsigned short* whi = (unsigned short*)scb;
    unsigned short* wlo = whi + 256 * 136;

    k_build_ad<<<dim3(258), dim3(256), 0, stream>>>(s4logdt, P, w_in, whi, wlo,
                                                    cls, mha_in_w, mha_in_b, qkb, qbb);
    k_pe<<<dim3(62 + 512), dim3(512), 0, stream>>>(P, Q, x, whi, wlo, w_in, b_in,
                                                   ln_in_g, ln_in_b, h, invn);
    k_lr<<<dim3(NLY * 64), dim3(256), 0, stream>>>(P, Q, s4B, s4C, Lb, Rb);
    k_kker<<<dim3(NLY * 256), dim3(256), 0, stream>>>(Lb, Rb, kker);

    for (int l = 0; l < NLY; ++l) {
        k_conv32<<<dim3(DD, 2), dim3(512), 0, stream>>>(h, kker, invn, s4D, l);
        k_ln<<<dim3(16, BB), dim3(256), 0, stream>>>(h, ln_g + l * DD, ln_b + l * DD, h, invn);
    }

    k_scores<<<dim3(8, BB), dim3(128), 0, stream>>>(h, cls, qkb, qbb, scb);
    k_ctx1<<<dim3(8, 4, BB), dim3(256), 0, stream>>>(h, scb, ctx1b, att0);
    k_head<<<dim3(BB), dim3(256), 0, stream>>>(ctx1b, att0, cls, mha_in_w, mha_in_b,
                                               mha_out_w, mha_out_b,
                                               head_w1, head_b1, head_w2, head_b2, (float*)d_out);
}